// Round 1
// baseline (664.390 us; speedup 1.0000x reference)
//
#include <hip/hip_runtime.h>

typedef unsigned short u16;
typedef __bf16 bf16x8 __attribute__((ext_vector_type(8)));
typedef float f32x4 __attribute__((ext_vector_type(4)));

constexpr int B_ = 2, T_ = 2048, D_ = 2048, H_ = 16, HD_ = 128;
constexpr int MROWS = B_ * T_;   // 4096
constexpr int KD = D_;           // 2048 (GEMM K)
constexpr int ND = D_;           // 2048 (GEMM N)
#define SCALE_F 0.08838834764831845f  // 1/sqrt(128)

__device__ __forceinline__ u16 f2bf(float f) {
  unsigned u = __float_as_uint(f);
  u += 0x7FFF + ((u >> 16) & 1);   // RNE; inputs never NaN
  return (u16)(u >> 16);
}

// async global->LDS, 16B per lane; LDS dest = wave-uniform base + lane*16
__device__ __forceinline__ void async16(const void* g, void* l) {
  __builtin_amdgcn_global_load_lds((__attribute__((address_space(1))) void*)g,
                                   (__attribute__((address_space(3))) void*)l,
                                   16, 0, 0);
}

__global__ void cvt_kernel(const float* __restrict__ in, u16* __restrict__ out, int n) {
  int i = (blockIdx.x * blockDim.x + threadIdx.x) * 4;
  if (i >= n) return;
  const float4 v = *(const float4*)(in + i);
  ushort4 h;
  h.x = f2bf(v.x); h.y = f2bf(v.y); h.z = f2bf(v.z); h.w = f2bf(v.w);
  *(ushort4*)(out + i) = h;
}

// C = A @ Bw^T + bias.  A: [MROWS,KD] bf16 row-major, Bw: [ND,KD] bf16 row-major.
// mode 0: bf16 out row-major [MROWS,ND]
// mode 1: bf16 out as Vt [B,H,HD,T]  (row=b*T+t, col=h*HD+d -> ((b*H+h)*HD+d)*T+t)
// mode 2: fp32 out row-major (final output)
__global__ __launch_bounds__(256) void gemm_nt(const u16* __restrict__ A,
                                               const u16* __restrict__ Bw,
                                               const float* __restrict__ bias,
                                               void* __restrict__ outp, int mode) {
  constexpr int BK = 32;
  __shared__ u16 As[128 * BK];
  __shared__ u16 Bs[128 * BK];
  const int tid = threadIdx.x;
  const int wave = tid >> 6;
  const int lane = tid & 63;
  const int quad = lane >> 4;
  const int l16 = lane & 15;
  const int wm = (wave >> 1) * 64;
  const int wn = (wave & 1) * 64;
  const int mBase = blockIdx.y * 128;
  const int nBase = blockIdx.x * 128;

  f32x4 acc[4][4] = {};

  // staging: wave handles 32 rows of A and of Bw; 2 calls each (16 rows/call)
  const int srow = wave * 32 + (lane >> 2);  // 4 lanes per 64B row-chunk
  const int soff = (lane & 3) * 8;
  const u16* Ag = A + (size_t)(mBase + srow) * KD + soff;
  const u16* Bg = Bw + (size_t)(nBase + srow) * KD + soff;
  u16* AsW0 = &As[(wave * 32) * BK];
  u16* AsW1 = &As[(wave * 32 + 16) * BK];
  u16* BsW0 = &Bs[(wave * 32) * BK];
  u16* BsW1 = &Bs[(wave * 32 + 16) * BK];

  for (int k0 = 0; k0 < KD; k0 += BK) {
    __syncthreads();                    // prior reads done before overwrite
    async16(Ag + k0, AsW0);
    async16(Ag + 16 * KD + k0, AsW1);
    async16(Bg + k0, BsW0);
    async16(Bg + 16 * KD + k0, BsW1);
    __syncthreads();                    // drains vmcnt -> LDS tiles ready

    bf16x8 a[4], b[4];
#pragma unroll
    for (int i = 0; i < 4; i++)
      a[i] = *(const bf16x8*)&As[(wm + i * 16 + l16) * BK + quad * 8];
#pragma unroll
    for (int j = 0; j < 4; j++)
      b[j] = *(const bf16x8*)&Bs[(wn + j * 16 + l16) * BK + quad * 8];
#pragma unroll
    for (int i = 0; i < 4; i++)
#pragma unroll
      for (int j = 0; j < 4; j++)
        acc[i][j] = __builtin_amdgcn_mfma_f32_16x16x32_bf16(a[i], b[j], acc[i][j], 0, 0, 0);
  }

  float* outF = (float*)outp;
  u16* outH = (u16*)outp;
#pragma unroll
  for (int i = 0; i < 4; i++) {
#pragma unroll
    for (int j = 0; j < 4; j++) {
      const int col = nBase + wn + j * 16 + l16;
      const float bv = bias[col];
#pragma unroll
      for (int r = 0; r < 4; r++) {
        const int row = mBase + wm + i * 16 + quad * 4 + r;
        const float v = acc[i][j][r] + bv;
        if (mode == 0) {
          outH[(size_t)row * ND + col] = f2bf(v);
        } else if (mode == 1) {
          const int bb = row >> 11;           // row / T
          const int t = row & (T_ - 1);
          const int h = col >> 7;             // col / HD
          const int d = col & (HD_ - 1);
          outH[(size_t)(((bb * H_ + h) << 7) + d) * T_ + t] = f2bf(v);
        } else {
          outF[(size_t)row * ND + col] = v;
        }
      }
    }
  }
}

// Flash attention. Q,K: [B*T, D] bf16 (head h at cols h*128..). Vt: [B,H,HD,T] bf16.
// O: [B*T, D] bf16. Block: 64 Q-rows (4 waves x 16-row strips), K-tiles of 64.
__global__ __launch_bounds__(256) void attn_kernel(const u16* __restrict__ Q,
                                                   const u16* __restrict__ Kc,
                                                   const u16* __restrict__ Vt,
                                                   u16* __restrict__ O) {
  __shared__ u16 Ks[64 * 128];   // [krow][d]
  __shared__ u16 Vs[128 * 64];   // [d][krow]  (transposed V tile)
  __shared__ u16 Ps[4 * 16 * 64];// per-wave P strips [q][krow]
  const int tid = threadIdx.x;
  const int wave = tid >> 6;
  const int lane = tid & 63;
  const int quad = lane >> 4;
  const int l16 = lane & 15;
  const int qt = blockIdx.x;     // q tile (64 rows)
  const int bh = blockIdx.y;
  const int b = bh >> 4;
  const int h = bh & 15;

  const int qrow0 = qt * 64 + wave * 16;

  // Q a-frags, resident whole kernel (4 x K=32 chunks over HD=128)
  bf16x8 qf[4];
  {
    const u16* Qp = Q + (size_t)(b * T_ + qrow0 + l16) * D_ + h * HD_;
#pragma unroll
    for (int kc = 0; kc < 4; kc++)
      qf[kc] = *(const bf16x8*)(Qp + kc * 32 + quad * 8);
  }

  f32x4 o[8] = {};
  float mrow[4], lrow[4];
#pragma unroll
  for (int r = 0; r < 4; r++) { mrow[r] = -__builtin_huge_valf(); lrow[r] = 0.f; }

  const u16* Kg = Kc + (size_t)(b * T_) * D_ + h * HD_;
  const u16* Vg = Vt + (size_t)((b * H_ + h) * HD_) * T_;
  u16* Pw = &Ps[wave * 16 * 64];

  for (int kt = 0; kt <= qt; kt++) {
    __syncthreads();  // prior iter's LDS reads done
    // stage K tile: wave stages rows [wave*16, +16); 4 calls x (4 rows = 1024B)
#pragma unroll
    for (int c = 0; c < 4; c++)
      async16(Kg + (size_t)(kt * 64 + wave * 16 + c * 4 + (lane >> 4)) * D_ + (lane & 15) * 8,
              &Ks[(wave * 16 + c * 4) * 128]);
    // stage Vt tile: wave stages d-rows [wave*32, +32); 4 calls x (8 rows = 1024B)
#pragma unroll
    for (int c = 0; c < 4; c++)
      async16(Vg + (size_t)(wave * 32 + c * 8 + (lane >> 3)) * T_ + kt * 64 + (lane & 7) * 8,
              &Vs[(wave * 32 + c * 8) * 64]);
    __syncthreads();  // tiles ready

    // S = Q K^T  (16x64 strip per wave, 4 n-tiles)
    f32x4 s[4];
#pragma unroll
    for (int nt = 0; nt < 4; nt++) {
      f32x4 a = {};
#pragma unroll
      for (int kc = 0; kc < 4; kc++) {
        bf16x8 kf = *(const bf16x8*)&Ks[(nt * 16 + l16) * 128 + kc * 32 + quad * 8];
        a = __builtin_amdgcn_mfma_f32_16x16x32_bf16(qf[kc], kf, a, 0, 0, 0);
      }
      s[nt] = a;
    }

    const bool diag = (kt == qt);
#pragma unroll
    for (int nt = 0; nt < 4; nt++)
#pragma unroll
      for (int r = 0; r < 4; r++) {
        float v = s[nt][r] * SCALE_F;
        if (diag) {
          const int colg = kt * 64 + nt * 16 + l16;
          const int rowg = qrow0 + quad * 4 + r;
          if (colg > rowg) v = -__builtin_huge_valf();
        }
        s[nt][r] = v;
      }

    // online softmax: row r lives in the 16 lanes of this quad
    float alpha[4];
#pragma unroll
    for (int r = 0; r < 4; r++) {
      float mx = fmaxf(fmaxf(s[0][r], s[1][r]), fmaxf(s[2][r], s[3][r]));
      mx = fmaxf(mx, __shfl_xor(mx, 1));
      mx = fmaxf(mx, __shfl_xor(mx, 2));
      mx = fmaxf(mx, __shfl_xor(mx, 4));
      mx = fmaxf(mx, __shfl_xor(mx, 8));
      const float mnew = fmaxf(mrow[r], mx);   // finite after first tile (col 0 always valid)
      alpha[r] = expf(mrow[r] - mnew);
      mrow[r] = mnew;
      float sum = 0.f;
#pragma unroll
      for (int nt = 0; nt < 4; nt++) {
        const float p = expf(s[nt][r] - mnew);
        s[nt][r] = p;
        sum += p;
      }
      sum += __shfl_xor(sum, 1);
      sum += __shfl_xor(sum, 2);
      sum += __shfl_xor(sum, 4);
      sum += __shfl_xor(sum, 8);
      lrow[r] = lrow[r] * alpha[r] + sum;
    }

#pragma unroll
    for (int dt = 0; dt < 8; dt++)
#pragma unroll
      for (int r = 0; r < 4; r++)
        o[dt][r] *= alpha[r];

    // P: C-layout regs -> LDS row-major [q][krow] (A-operand friendly)
#pragma unroll
    for (int nt = 0; nt < 4; nt++)
#pragma unroll
      for (int r = 0; r < 4; r++)
        Pw[(quad * 4 + r) * 64 + nt * 16 + l16] = f2bf(s[nt][r]);

    __syncthreads();  // P visible (uniform across waves; also orders within wave)

    // O += P @ V   (P a-frags 16x64, Vt b-frags contiguous)
    bf16x8 pf[2];
#pragma unroll
    for (int kc = 0; kc < 2; kc++)
      pf[kc] = *(const bf16x8*)&Pw[l16 * 64 + kc * 32 + quad * 8];
#pragma unroll
    for (int dt = 0; dt < 8; dt++) {
#pragma unroll
      for (int kc = 0; kc < 2; kc++) {
        bf16x8 vf = *(const bf16x8*)&Vs[(dt * 16 + l16) * 64 + kc * 32 + quad * 8];
        o[dt] = __builtin_amdgcn_mfma_f32_16x16x32_bf16(pf[kc], vf, o[dt], 0, 0, 0);
      }
    }
  }

  // epilogue: normalize and store O (bf16, [B*T, D], col = h*128 + d)
#pragma unroll
  for (int dt = 0; dt < 8; dt++)
#pragma unroll
    for (int r = 0; r < 4; r++) {
      const int rowg = b * T_ + qrow0 + quad * 4 + r;
      const int col = h * HD_ + dt * 16 + l16;
      O[(size_t)rowg * D_ + col] = f2bf(o[dt][r] / lrow[r]);
    }
}

extern "C" void kernel_launch(void* const* d_in, const int* in_sizes, int n_in,
                              void* d_out, int out_size, void* d_ws, size_t ws_size,
                              hipStream_t stream) {
  (void)in_sizes; (void)n_in; (void)out_size; (void)ws_size;
  const float* x  = (const float*)d_in[0];
  // d_in[1] = mask (deterministic causal; implemented analytically)
  const float* wq = (const float*)d_in[2];
  const float* bq = (const float*)d_in[3];
  const float* wk = (const float*)d_in[4];
  const float* bk = (const float*)d_in[5];
  const float* wv = (const float*)d_in[6];
  const float* bv = (const float*)d_in[7];
  const float* wo = (const float*)d_in[8];
  const float* bo = (const float*)d_in[9];

  // workspace layout (u16 elements): 112 MB total
  u16* ws  = (u16*)d_ws;
  u16* xb  = ws;                 // 8388608  (x bf16)
  u16* wqb = ws + 8388608;       // 4194304
  u16* wkb = ws + 12582912;
  u16* wvb = ws + 16777216;
  u16* wob = ws + 20971520;
  u16* Qb  = ws + 25165824;      // 8388608
  u16* Kb  = ws + 33554432;
  u16* Vtb = ws + 41943040;      // [B,H,HD,T]
  u16* Ob  = ws + 50331648;      // attention out bf16

  cvt_kernel<<<8192, 256, 0, stream>>>(x,  xb,  8388608);
  cvt_kernel<<<4096, 256, 0, stream>>>(wq, wqb, 4194304);
  cvt_kernel<<<4096, 256, 0, stream>>>(wk, wkb, 4194304);
  cvt_kernel<<<4096, 256, 0, stream>>>(wv, wvb, 4194304);
  cvt_kernel<<<4096, 256, 0, stream>>>(wo, wob, 4194304);

  dim3 gg(ND / 128, MROWS / 128);  // (16, 32)
  gemm_nt<<<gg, 256, 0, stream>>>(xb, wqb, bq, Qb, 0);
  gemm_nt<<<gg, 256, 0, stream>>>(xb, wkb, bk, Kb, 0);
  gemm_nt<<<gg, 256, 0, stream>>>(xb, wvb, bv, Vtb, 1);
  attn_kernel<<<dim3(T_ / 64, B_ * H_), 256, 0, stream>>>(Qb, Kb, Vtb, Ob);
  gemm_nt<<<gg, 256, 0, stream>>>(Ob, wob, bo, d_out, 2);
}

// Round 2
// 412.330 us; speedup vs baseline: 1.6113x; 1.6113x over previous
//
#include <hip/hip_runtime.h>

typedef unsigned short u16;
typedef __bf16 bf16x8 __attribute__((ext_vector_type(8)));
typedef float f32x4 __attribute__((ext_vector_type(4)));

constexpr int B_ = 2, T_ = 2048, D_ = 2048, H_ = 16, HD_ = 128;
constexpr int MROWS = B_ * T_;   // 4096
constexpr int KD = D_;
constexpr int ND = D_;
// softmax in exp2 domain: logits pre-scaled by 1/sqrt(128) * log2(e)
#define SL2E (0.08838834764831845f * 1.4426950408889634f)

__device__ __forceinline__ u16 f2bf(float f) {
  unsigned u = __float_as_uint(f);
  u += 0x7FFF + ((u >> 16) & 1);   // RNE; inputs never NaN
  return (u16)(u >> 16);
}

__device__ __forceinline__ float fexp2(float x) { return __builtin_amdgcn_exp2f(x); }

// async global->LDS, 16B per lane (contiguous dest only — GEMM staging)
__device__ __forceinline__ void async16(const void* g, void* l) {
  __builtin_amdgcn_global_load_lds((__attribute__((address_space(1))) void*)g,
                                   (__attribute__((address_space(3))) void*)l,
                                   16, 0, 0);
}

__global__ void cvt_kernel(const float* __restrict__ in, u16* __restrict__ out, int n) {
  int i = (blockIdx.x * blockDim.x + threadIdx.x) * 4;
  if (i >= n) return;
  const float4 v = *(const float4*)(in + i);
  ushort4 h;
  h.x = f2bf(v.x); h.y = f2bf(v.y); h.z = f2bf(v.z); h.w = f2bf(v.w);
  *(ushort4*)(out + i) = h;
}

// 4 weight matrices in one dispatch (grid.y selects)
__global__ void cvt4_kernel(const float* __restrict__ w0, const float* __restrict__ w1,
                            const float* __restrict__ w2, const float* __restrict__ w3,
                            u16* __restrict__ o0, u16* __restrict__ o1,
                            u16* __restrict__ o2, u16* __restrict__ o3, int n) {
  const float* in = blockIdx.y == 0 ? w0 : blockIdx.y == 1 ? w1 : blockIdx.y == 2 ? w2 : w3;
  u16* out = blockIdx.y == 0 ? o0 : blockIdx.y == 1 ? o1 : blockIdx.y == 2 ? o2 : o3;
  int i = (blockIdx.x * blockDim.x + threadIdx.x) * 4;
  if (i >= n) return;
  const float4 v = *(const float4*)(in + i);
  ushort4 h;
  h.x = f2bf(v.x); h.y = f2bf(v.y); h.z = f2bf(v.z); h.w = f2bf(v.w);
  *(ushort4*)(out + i) = h;
}

// ---- GEMM core: C = A @ Bw^T + bias. A:[M,K] bf16 rm, Bw:[N,K] bf16 rm. ----
// mode 0: bf16 rm; mode 1: bf16 Vt [B,H,HD,T]; mode 2: fp32 rm
template <int MODE>
__device__ __forceinline__ void gemm_body(const u16* __restrict__ A,
                                          const u16* __restrict__ Bw,
                                          const float* __restrict__ bias,
                                          void* __restrict__ outp,
                                          u16* As, u16* Bs) {
  constexpr int BK = 32;
  const int tid = threadIdx.x;
  const int wave = tid >> 6;
  const int lane = tid & 63;
  const int quad = lane >> 4;
  const int l16 = lane & 15;
  const int wm = (wave >> 1) * 64;
  const int wn = (wave & 1) * 64;
  const int mBase = blockIdx.y * 128;
  const int nBase = blockIdx.x * 128;

  f32x4 acc[4][4] = {};

  const int srow = wave * 32 + (lane >> 2);
  const int soff = (lane & 3) * 8;
  const u16* Ag = A + (size_t)(mBase + srow) * KD + soff;
  const u16* Bg = Bw + (size_t)(nBase + srow) * KD + soff;
  u16* AsW0 = &As[(wave * 32) * BK];
  u16* AsW1 = &As[(wave * 32 + 16) * BK];
  u16* BsW0 = &Bs[(wave * 32) * BK];
  u16* BsW1 = &Bs[(wave * 32 + 16) * BK];

  for (int k0 = 0; k0 < KD; k0 += BK) {
    __syncthreads();
    async16(Ag + k0, AsW0);
    async16(Ag + 16 * KD + k0, AsW1);
    async16(Bg + k0, BsW0);
    async16(Bg + 16 * KD + k0, BsW1);
    __syncthreads();

    bf16x8 a[4], b[4];
#pragma unroll
    for (int i = 0; i < 4; i++)
      a[i] = *(const bf16x8*)&As[(wm + i * 16 + l16) * BK + quad * 8];
#pragma unroll
    for (int j = 0; j < 4; j++)
      b[j] = *(const bf16x8*)&Bs[(wn + j * 16 + l16) * BK + quad * 8];
#pragma unroll
    for (int i = 0; i < 4; i++)
#pragma unroll
      for (int j = 0; j < 4; j++)
        acc[i][j] = __builtin_amdgcn_mfma_f32_16x16x32_bf16(a[i], b[j], acc[i][j], 0, 0, 0);
  }

  float* outF = (float*)outp;
  u16* outH = (u16*)outp;
#pragma unroll
  for (int i = 0; i < 4; i++) {
#pragma unroll
    for (int j = 0; j < 4; j++) {
      const int col = nBase + wn + j * 16 + l16;
      const float bv = bias[col];
#pragma unroll
      for (int r = 0; r < 4; r++) {
        const int row = mBase + wm + i * 16 + quad * 4 + r;
        const float v = acc[i][j][r] + bv;
        if (MODE == 0) {
          outH[(size_t)row * ND + col] = f2bf(v);
        } else if (MODE == 1) {
          const int bb = row >> 11;
          const int t = row & (T_ - 1);
          const int h = col >> 7;
          const int d = col & (HD_ - 1);
          outH[(size_t)(((bb * H_ + h) << 7) + d) * T_ + t] = f2bf(v);
        } else {
          outF[(size_t)row * ND + col] = v;
        }
      }
    }
  }
}

// fused Q/K/V projection: grid.z picks weight/bias/dest
__global__ __launch_bounds__(256) void gemm_qkv(const u16* __restrict__ A,
                                                const u16* __restrict__ Wq, const u16* __restrict__ Wk,
                                                const u16* __restrict__ Wv,
                                                const float* __restrict__ bq, const float* __restrict__ bk,
                                                const float* __restrict__ bv,
                                                u16* __restrict__ Qo, u16* __restrict__ Ko,
                                                u16* __restrict__ Vo) {
  __shared__ u16 As[128 * 32];
  __shared__ u16 Bs[128 * 32];
  const int z = blockIdx.z;
  const u16* Bw = z == 0 ? Wq : z == 1 ? Wk : Wv;
  const float* bias = z == 0 ? bq : z == 1 ? bk : bv;
  if (z == 2)
    gemm_body<1>(A, Bw, bias, (void*)Vo, As, Bs);
  else
    gemm_body<0>(A, Bw, bias, (void*)(z == 0 ? Qo : Ko), As, Bs);
}

__global__ __launch_bounds__(256) void gemm_out(const u16* __restrict__ A, const u16* __restrict__ Bw,
                                                const float* __restrict__ bias, float* __restrict__ outp) {
  __shared__ u16 As[128 * 32];
  __shared__ u16 Bs[128 * 32];
  gemm_body<2>(A, Bw, bias, (void*)outp, As, Bs);
}

// ---- Flash attention, paired q-tiles for causal load balance. ----
// Q,K: [B*T, D] bf16 (head h at cols h*128..). Vt: [B,H,HD,T] bf16. O: [B*T,D] bf16.
// grid (T/128=16, B*H=32); block 256. Block x handles q-tiles {x, 31-x} (64 rows each).
// LDS strides padded to odd multiples of 16B -> conflict-free ds_read_b128 columns.
constexpr int KSTR = 136;  // K-tile row stride (u16), 17 x 16B groups
constexpr int VSTR = 72;   // V/P row stride (u16), 9 x 16B groups

__global__ __launch_bounds__(256) void attn_kernel(const u16* __restrict__ Q,
                                                   const u16* __restrict__ Kc,
                                                   const u16* __restrict__ Vt,
                                                   u16* __restrict__ O) {
  __shared__ u16 Ks[64 * KSTR];        // [krow][d]
  __shared__ u16 Vs[128 * VSTR];       // [d][krow]
  __shared__ u16 Ps[4 * 16 * VSTR];    // per-wave P strip [q][krow]
  const int tid = threadIdx.x;
  const int wave = tid >> 6;
  const int lane = tid & 63;
  const int quad = lane >> 4;
  const int l16 = lane & 15;
  const int lo = blockIdx.x;           // q-tile indices (64-row units)
  const int hi = 31 - lo;
  const int bh = blockIdx.y;
  const int b = bh >> 4;
  const int h = bh & 15;

  const int tIdx[2] = {lo, hi};

  // resident Q a-frags for both tiles
  bf16x8 qf[2][4];
#pragma unroll
  for (int t = 0; t < 2; t++) {
    const u16* Qp = Q + (size_t)(b * T_ + tIdx[t] * 64 + wave * 16 + l16) * D_ + h * HD_;
#pragma unroll
    for (int kc = 0; kc < 4; kc++)
      qf[t][kc] = *(const bf16x8*)(Qp + kc * 32 + quad * 8);
  }

  f32x4 o[2][8] = {};
  float mrow[2][4], lrow[2][4];
#pragma unroll
  for (int t = 0; t < 2; t++)
#pragma unroll
    for (int r = 0; r < 4; r++) { mrow[t][r] = -__builtin_huge_valf(); lrow[t][r] = 0.f; }

  const u16* Kg = Kc + (size_t)(b * T_) * D_ + h * HD_;
  const u16* Vg = Vt + (size_t)((b * H_ + h) * HD_) * T_;
  u16* Pw = &Ps[wave * 16 * VSTR];

  for (int kt = 0; kt <= hi; kt++) {
    __syncthreads();   // prior iter's K/V reads done before overwrite
    // stage K tile 64x128 (pad KSTR): 4 rounds, 16 rows/round, 16 lanes/row
    {
      uint4 kv[4], vv[4];
      const int krow = tid >> 4, kc16 = tid & 15;
      const int vrow = tid >> 3, vc16 = tid & 7;
#pragma unroll
      for (int rr = 0; rr < 4; rr++)
        kv[rr] = *(const uint4*)(Kg + (size_t)(kt * 64 + rr * 16 + krow) * D_ + kc16 * 8);
#pragma unroll
      for (int rr = 0; rr < 4; rr++)
        vv[rr] = *(const uint4*)(Vg + (size_t)(rr * 32 + vrow) * T_ + kt * 64 + vc16 * 8);
#pragma unroll
      for (int rr = 0; rr < 4; rr++)
        *(uint4*)&Ks[(rr * 16 + krow) * KSTR + kc16 * 8] = kv[rr];
#pragma unroll
      for (int rr = 0; rr < 4; rr++)
        *(uint4*)&Vs[(rr * 32 + vrow) * VSTR + vc16 * 8] = vv[rr];
    }
    __syncthreads();   // tiles visible to all waves

#pragma unroll
    for (int t = 0; t < 2; t++) {
      if (t == 0 && kt > lo) continue;   // lo tile done (block-uniform branch)
      const int qrow0 = tIdx[t] * 64 + wave * 16;

      // S = Q K^T, 16x64 strip
      f32x4 s[4];
#pragma unroll
      for (int nt = 0; nt < 4; nt++) {
        f32x4 a = {};
#pragma unroll
        for (int kc = 0; kc < 4; kc++) {
          bf16x8 kf = *(const bf16x8*)&Ks[(nt * 16 + l16) * KSTR + kc * 32 + quad * 8];
          a = __builtin_amdgcn_mfma_f32_16x16x32_bf16(qf[t][kc], kf, a, 0, 0, 0);
        }
        s[nt] = a;
      }

      const bool diag = (kt == tIdx[t]);
#pragma unroll
      for (int nt = 0; nt < 4; nt++)
#pragma unroll
        for (int r = 0; r < 4; r++) {
          float v = s[nt][r] * SL2E;   // exp2-domain logits
          if (diag) {
            const int colg = nt * 16 + l16;
            const int rowg = wave * 16 + quad * 4 + r;   // same tile -> compare within tile
            if (colg > rowg) v = -__builtin_huge_valf();
          }
          s[nt][r] = v;
        }

      float alpha[4];
#pragma unroll
      for (int r = 0; r < 4; r++) {
        float mx = fmaxf(fmaxf(s[0][r], s[1][r]), fmaxf(s[2][r], s[3][r]));
        mx = fmaxf(mx, __shfl_xor(mx, 1));
        mx = fmaxf(mx, __shfl_xor(mx, 2));
        mx = fmaxf(mx, __shfl_xor(mx, 4));
        mx = fmaxf(mx, __shfl_xor(mx, 8));
        const float mnew = fmaxf(mrow[t][r], mx);
        alpha[r] = fexp2(mrow[t][r] - mnew);
        mrow[t][r] = mnew;
        float sum = 0.f;
#pragma unroll
        for (int nt = 0; nt < 4; nt++) {
          const float p = fexp2(s[nt][r] - mnew);
          s[nt][r] = p;
          sum += p;
        }
        sum += __shfl_xor(sum, 1);
        sum += __shfl_xor(sum, 2);
        sum += __shfl_xor(sum, 4);
        sum += __shfl_xor(sum, 8);
        lrow[t][r] = lrow[t][r] * alpha[r] + sum;
      }

#pragma unroll
      for (int dt = 0; dt < 8; dt++)
#pragma unroll
        for (int r = 0; r < 4; r++)
          o[t][dt][r] *= alpha[r];

      // P: C-layout -> wave-private LDS strip [q][krow] (A-operand layout)
#pragma unroll
      for (int nt = 0; nt < 4; nt++)
#pragma unroll
        for (int r = 0; r < 4; r++)
          Pw[(quad * 4 + r) * VSTR + nt * 16 + l16] = f2bf(s[nt][r]);
      // no barrier: strip is wave-private; in-wave lgkmcnt ordering suffices

      bf16x8 pf[2];
#pragma unroll
      for (int kc = 0; kc < 2; kc++)
        pf[kc] = *(const bf16x8*)&Pw[l16 * VSTR + kc * 32 + quad * 8];
#pragma unroll
      for (int dt = 0; dt < 8; dt++) {
#pragma unroll
        for (int kc = 0; kc < 2; kc++) {
          bf16x8 vf = *(const bf16x8*)&Vs[(dt * 16 + l16) * VSTR + kc * 32 + quad * 8];
          o[t][dt] = __builtin_amdgcn_mfma_f32_16x16x32_bf16(pf[kc], vf, o[t][dt], 0, 0, 0);
        }
      }
    }
  }

#pragma unroll
  for (int t = 0; t < 2; t++)
#pragma unroll
    for (int dt = 0; dt < 8; dt++)
#pragma unroll
      for (int r = 0; r < 4; r++) {
        const int rowg = b * T_ + tIdx[t] * 64 + wave * 16 + quad * 4 + r;
        const int col = h * HD_ + dt * 16 + l16;
        O[(size_t)rowg * D_ + col] = f2bf(o[t][dt][r] / lrow[t][r]);
      }
}

extern "C" void kernel_launch(void* const* d_in, const int* in_sizes, int n_in,
                              void* d_out, int out_size, void* d_ws, size_t ws_size,
                              hipStream_t stream) {
  (void)in_sizes; (void)n_in; (void)out_size; (void)ws_size;
  const float* x  = (const float*)d_in[0];
  const float* wq = (const float*)d_in[2];
  const float* bq = (const float*)d_in[3];
  const float* wk = (const float*)d_in[4];
  const float* bk = (const float*)d_in[5];
  const float* wv = (const float*)d_in[6];
  const float* bv = (const float*)d_in[7];
  const float* wo = (const float*)d_in[8];
  const float* bo = (const float*)d_in[9];

  u16* ws  = (u16*)d_ws;
  u16* xb  = ws;                 // 8388608
  u16* wqb = ws + 8388608;
  u16* wkb = ws + 12582912;
  u16* wvb = ws + 16777216;
  u16* wob = ws + 20971520;
  u16* Qb  = ws + 25165824;
  u16* Kb  = ws + 33554432;
  u16* Vtb = ws + 41943040;      // [B,H,HD,T]
  u16* Ob  = ws + 50331648;

  cvt_kernel<<<8192, 256, 0, stream>>>(x, xb, 8388608);
  cvt4_kernel<<<dim3(4096, 4), 256, 0, stream>>>(wq, wk, wv, wo, wqb, wkb, wvb, wob, 4194304);

  dim3 gg(ND / 128, MROWS / 128, 3);   // (16, 32, 3)
  gemm_qkv<<<gg, 256, 0, stream>>>(xb, wqb, wkb, wvb, bq, bk, bv, Qb, Kb, Vtb);
  attn_kernel<<<dim3(16, B_ * H_), 256, 0, stream>>>(Qb, Kb, Vtb, Ob);
  gemm_out<<<dim3(ND / 128, MROWS / 128), 256, 0, stream>>>(Ob, wob, bo, (float*)d_out);
}

// Round 3
// 403.469 us; speedup vs baseline: 1.6467x; 1.0220x over previous
//
#include <hip/hip_runtime.h>

typedef unsigned short u16;
typedef __bf16 bf16x8 __attribute__((ext_vector_type(8)));
typedef float f32x4 __attribute__((ext_vector_type(4)));

constexpr int B_ = 2, T_ = 2048, D_ = 2048, H_ = 16, HD_ = 128;
constexpr int MROWS = B_ * T_;   // 4096
constexpr int KD = D_;
constexpr int ND = D_;
// softmax in exp2 domain: logits pre-scaled by 1/sqrt(128) * log2(e)
#define SL2E (0.08838834764831845f * 1.4426950408889634f)

__device__ __forceinline__ u16 f2bf(float f) {
  unsigned u = __float_as_uint(f);
  u += 0x7FFF + ((u >> 16) & 1);   // RNE; inputs never NaN
  return (u16)(u >> 16);
}

__device__ __forceinline__ float fexp2(float x) { return __builtin_amdgcn_exp2f(x); }

// async global->LDS, 16B per lane (contiguous dest only — GEMM staging)
__device__ __forceinline__ void async16(const void* g, void* l) {
  __builtin_amdgcn_global_load_lds((__attribute__((address_space(1))) void*)g,
                                   (__attribute__((address_space(3))) void*)l,
                                   16, 0, 0);
}

__global__ void cvt_kernel(const float* __restrict__ in, u16* __restrict__ out, int n) {
  int i = (blockIdx.x * blockDim.x + threadIdx.x) * 4;
  if (i >= n) return;
  const float4 v = *(const float4*)(in + i);
  ushort4 h;
  h.x = f2bf(v.x); h.y = f2bf(v.y); h.z = f2bf(v.z); h.w = f2bf(v.w);
  *(ushort4*)(out + i) = h;
}

__global__ void cvt4_kernel(const float* __restrict__ w0, const float* __restrict__ w1,
                            const float* __restrict__ w2, const float* __restrict__ w3,
                            u16* __restrict__ o0, u16* __restrict__ o1,
                            u16* __restrict__ o2, u16* __restrict__ o3, int n) {
  const float* in = blockIdx.y == 0 ? w0 : blockIdx.y == 1 ? w1 : blockIdx.y == 2 ? w2 : w3;
  u16* out = blockIdx.y == 0 ? o0 : blockIdx.y == 1 ? o1 : blockIdx.y == 2 ? o2 : o3;
  int i = (blockIdx.x * blockDim.x + threadIdx.x) * 4;
  if (i >= n) return;
  const float4 v = *(const float4*)(in + i);
  ushort4 h;
  h.x = f2bf(v.x); h.y = f2bf(v.y); h.z = f2bf(v.z); h.w = f2bf(v.w);
  *(ushort4*)(out + i) = h;
}

// ---- GEMM core: C = A @ Bw^T + bias. A:[M,K] bf16 rm, Bw:[N,K] bf16 rm. ----
// LDS tiles XOR-swizzled: data for (row, chunk g of 8 u16) stored at chunk
// s = g ^ ((row>>1)&3). Staging permutes global source chunk per lane
// (coalescing preserved: same 1KB per async16 call); fragment reads use
// chunk = quad ^ ((l16>>1)&3) -> every 8-lane phase hits 8 distinct 16B groups.
template <int MODE>
__device__ __forceinline__ void gemm_body(const u16* __restrict__ A,
                                          const u16* __restrict__ Bw,
                                          const float* __restrict__ bias,
                                          void* __restrict__ outp,
                                          u16* As, u16* Bs) {
  constexpr int BK = 32;
  const int tid = threadIdx.x;
  const int wave = tid >> 6;
  const int lane = tid & 63;
  const int quad = lane >> 4;
  const int l16 = lane & 15;
  const int wm = (wave >> 1) * 64;
  const int wn = (wave & 1) * 64;
  const int mBase = blockIdx.y * 128;
  const int nBase = blockIdx.x * 128;

  f32x4 acc[4][4] = {};

  const int srow = wave * 32 + (lane >> 2);
  // swizzled global chunk for this lane's LDS slot: ((lane&3) ^ ((lane>>3)&3))
  const int soff = ((lane & 3) ^ ((lane >> 3) & 3)) * 8;
  const u16* Ag = A + (size_t)(mBase + srow) * KD + soff;
  const u16* Bg = Bw + (size_t)(nBase + srow) * KD + soff;
  u16* AsW0 = &As[(wave * 32) * BK];
  u16* AsW1 = &As[(wave * 32 + 16) * BK];
  u16* BsW0 = &Bs[(wave * 32) * BK];
  u16* BsW1 = &Bs[(wave * 32 + 16) * BK];

  const int sw = (quad ^ ((l16 >> 1) & 3)) * 8;   // swizzled read chunk

  for (int k0 = 0; k0 < KD; k0 += BK) {
    __syncthreads();
    async16(Ag + k0, AsW0);
    async16(Ag + 16 * KD + k0, AsW1);
    async16(Bg + k0, BsW0);
    async16(Bg + 16 * KD + k0, BsW1);
    __syncthreads();

    bf16x8 a[4], b[4];
#pragma unroll
    for (int i = 0; i < 4; i++)
      a[i] = *(const bf16x8*)&As[(wm + i * 16 + l16) * BK + sw];
#pragma unroll
    for (int j = 0; j < 4; j++)
      b[j] = *(const bf16x8*)&Bs[(wn + j * 16 + l16) * BK + sw];
#pragma unroll
    for (int i = 0; i < 4; i++)
#pragma unroll
      for (int j = 0; j < 4; j++)
        acc[i][j] = __builtin_amdgcn_mfma_f32_16x16x32_bf16(a[i], b[j], acc[i][j], 0, 0, 0);
  }

  float* outF = (float*)outp;
  u16* outH = (u16*)outp;
#pragma unroll
  for (int i = 0; i < 4; i++) {
#pragma unroll
    for (int j = 0; j < 4; j++) {
      const int col = nBase + wn + j * 16 + l16;
      const float bv = bias[col];
#pragma unroll
      for (int r = 0; r < 4; r++) {
        const int row = mBase + wm + i * 16 + quad * 4 + r;
        const float v = acc[i][j][r] + bv;
        if (MODE == 0) {
          outH[(size_t)row * ND + col] = f2bf(v);
        } else if (MODE == 1) {
          const int bb = row >> 11;
          const int t = row & (T_ - 1);
          const int h = col >> 7;
          const int d = col & (HD_ - 1);
          outH[(size_t)(((bb * H_ + h) << 7) + d) * T_ + t] = f2bf(v);
        } else {
          outF[(size_t)row * ND + col] = v;
        }
      }
    }
  }
}

__global__ __launch_bounds__(256) void gemm_qkv(const u16* __restrict__ A,
                                                const u16* __restrict__ Wq, const u16* __restrict__ Wk,
                                                const u16* __restrict__ Wv,
                                                const float* __restrict__ bq, const float* __restrict__ bk,
                                                const float* __restrict__ bv,
                                                u16* __restrict__ Qo, u16* __restrict__ Ko,
                                                u16* __restrict__ Vo) {
  __shared__ u16 As[128 * 32];
  __shared__ u16 Bs[128 * 32];
  const int z = blockIdx.z;
  const u16* Bw = z == 0 ? Wq : z == 1 ? Wk : Wv;
  const float* bias = z == 0 ? bq : z == 1 ? bk : bv;
  if (z == 2)
    gemm_body<1>(A, Bw, bias, (void*)Vo, As, Bs);
  else
    gemm_body<0>(A, Bw, bias, (void*)(z == 0 ? Qo : Ko), As, Bs);
}

__global__ __launch_bounds__(256) void gemm_out(const u16* __restrict__ A, const u16* __restrict__ Bw,
                                                const float* __restrict__ bias, float* __restrict__ outp) {
  __shared__ u16 As[128 * 32];
  __shared__ u16 Bs[128 * 32];
  gemm_body<2>(A, Bw, bias, (void*)outp, As, Bs);
}

// ---- Flash attention (S^T formulation), paired q-tiles. ----
// Computes S^T = K·Q^T per tile (swap MFMA operands; same LDS reads) so the
// C-layout puts ONE q-row per lane (q = l16): softmax reduces with 2 shuffles,
// m/l are scalar per lane, and P packs as 4x ds_write_b64 per tile.
constexpr int KSTR = 136;  // K-tile row stride (u16), 17 x 16B groups
constexpr int VSTR = 72;   // V/P row stride (u16), 9 x 16B groups

__global__ __launch_bounds__(256) void attn_kernel(const u16* __restrict__ Q,
                                                   const u16* __restrict__ Kc,
                                                   const u16* __restrict__ Vt,
                                                   u16* __restrict__ O) {
  __shared__ u16 Ks[64 * KSTR];        // [krow][d]
  __shared__ u16 Vs[128 * VSTR];       // [d][krow]
  __shared__ u16 Ps[4 * 16 * VSTR];    // per-wave P strip [q][krow]
  const int tid = threadIdx.x;
  const int wave = tid >> 6;
  const int lane = tid & 63;
  const int quad = lane >> 4;
  const int l16 = lane & 15;
  const int lo = blockIdx.x;
  const int hi = 31 - lo;
  const int bh = blockIdx.y;
  const int b = bh >> 4;
  const int h = bh & 15;

  const int tIdx[2] = {lo, hi};

  // resident Q fragments (used as B-operand: B[k=d][n=q=l16])
  bf16x8 qf[2][4];
#pragma unroll
  for (int t = 0; t < 2; t++) {
    const u16* Qp = Q + (size_t)(b * T_ + tIdx[t] * 64 + wave * 16 + l16) * D_ + h * HD_;
#pragma unroll
    for (int kc = 0; kc < 4; kc++)
      qf[t][kc] = *(const bf16x8*)(Qp + kc * 32 + quad * 8);
  }

  f32x4 o[2][8] = {};
  float mrow[2], lrow[2];
#pragma unroll
  for (int t = 0; t < 2; t++) { mrow[t] = -__builtin_huge_valf(); lrow[t] = 0.f; }

  const u16* Kg = Kc + (size_t)(b * T_) * D_ + h * HD_;
  const u16* Vg = Vt + (size_t)((b * H_ + h) * HD_) * T_;
  u16* Pw = &Ps[wave * 16 * VSTR];

  for (int kt = 0; kt <= hi; kt++) {
    __syncthreads();
    {
      uint4 kv[4], vv[4];
      const int krow = tid >> 4, kc16 = tid & 15;
      const int vrow = tid >> 3, vc16 = tid & 7;
#pragma unroll
      for (int rr = 0; rr < 4; rr++)
        kv[rr] = *(const uint4*)(Kg + (size_t)(kt * 64 + rr * 16 + krow) * D_ + kc16 * 8);
#pragma unroll
      for (int rr = 0; rr < 4; rr++)
        vv[rr] = *(const uint4*)(Vg + (size_t)(rr * 32 + vrow) * T_ + kt * 64 + vc16 * 8);
#pragma unroll
      for (int rr = 0; rr < 4; rr++)
        *(uint4*)&Ks[(rr * 16 + krow) * KSTR + kc16 * 8] = kv[rr];
#pragma unroll
      for (int rr = 0; rr < 4; rr++)
        *(uint4*)&Vs[(rr * 32 + vrow) * VSTR + vc16 * 8] = vv[rr];
    }
    __syncthreads();

#pragma unroll
    for (int t = 0; t < 2; t++) {
      if (t == 0 && kt > lo) continue;   // lo tile done (block-uniform)

      // S^T = K·Q^T: A = K rows (m=kcol=l16), B = Q^T (n=q=l16)
      // C layout: col=l16 -> q, row=quad*4+r -> kcol (within nt*16 block)
      f32x4 st[4];
#pragma unroll
      for (int nt = 0; nt < 4; nt++) {
        f32x4 a = {};
#pragma unroll
        for (int kc = 0; kc < 4; kc++) {
          bf16x8 kf = *(const bf16x8*)&Ks[(nt * 16 + l16) * KSTR + kc * 32 + quad * 8];
          a = __builtin_amdgcn_mfma_f32_16x16x32_bf16(kf, qf[t][kc], a, 0, 0, 0);
        }
        st[nt] = a;
      }

      const bool diag = (kt == tIdx[t]);
#pragma unroll
      for (int nt = 0; nt < 4; nt++)
#pragma unroll
        for (int r = 0; r < 4; r++) {
          float v = st[nt][r] * SL2E;
          if (diag) {
            const int kcol = nt * 16 + quad * 4 + r;       // within tile
            const int qrow = wave * 16 + l16;              // within tile
            if (kcol > qrow) v = -__builtin_huge_valf();
          }
          st[nt][r] = v;
        }

      // online softmax: per lane, all 16 st values share q = l16.
      // lanes {l16, l16+16, l16+32, l16+48} hold the 4 kcol quadrants.
      float mx = st[0][0];
#pragma unroll
      for (int nt = 0; nt < 4; nt++)
#pragma unroll
        for (int r = 0; r < 4; r++) mx = fmaxf(mx, st[nt][r]);
      mx = fmaxf(mx, __shfl_xor(mx, 16));
      mx = fmaxf(mx, __shfl_xor(mx, 32));
      const float mnew = fmaxf(mrow[t], mx);
      const float alpha = fexp2(mrow[t] - mnew);
      mrow[t] = mnew;
      float sum = 0.f;
#pragma unroll
      for (int nt = 0; nt < 4; nt++)
#pragma unroll
        for (int r = 0; r < 4; r++) {
          const float p = fexp2(st[nt][r] - mnew);
          st[nt][r] = p;
          sum += p;
        }
      sum += __shfl_xor(sum, 16);
      sum += __shfl_xor(sum, 32);
      lrow[t] = lrow[t] * alpha + sum;

      // broadcast alpha for o-rescale: o rows are q = quad*4+r
      float af[4];
#pragma unroll
      for (int r = 0; r < 4; r++) af[r] = __shfl(alpha, quad * 4 + r);
#pragma unroll
      for (int dt = 0; dt < 8; dt++)
#pragma unroll
        for (int r = 0; r < 4; r++)
          o[t][dt][r] *= af[r];

      // P store: [q=l16][k = nt*16 + quad*4 + r] -> 4 consecutive u16 per nt
#pragma unroll
      for (int nt = 0; nt < 4; nt++) {
        ushort4 pk;
        pk.x = f2bf(st[nt][0]); pk.y = f2bf(st[nt][1]);
        pk.z = f2bf(st[nt][2]); pk.w = f2bf(st[nt][3]);
        *(ushort4*)&Pw[l16 * VSTR + nt * 16 + quad * 4] = pk;
      }
      // wave-private strip: in-wave lgkmcnt ordering suffices (no barrier)

      bf16x8 pf[2];
#pragma unroll
      for (int kc = 0; kc < 2; kc++)
        pf[kc] = *(const bf16x8*)&Pw[l16 * VSTR + kc * 32 + quad * 8];
#pragma unroll
      for (int dt = 0; dt < 8; dt++) {
#pragma unroll
        for (int kc = 0; kc < 2; kc++) {
          bf16x8 vf = *(const bf16x8*)&Vs[(dt * 16 + l16) * VSTR + kc * 32 + quad * 8];
          o[t][dt] = __builtin_amdgcn_mfma_f32_16x16x32_bf16(pf[kc], vf, o[t][dt], 0, 0, 0);
        }
      }
    }
  }

  // epilogue: broadcast l for rows q=quad*4+r, normalize, store
#pragma unroll
  for (int t = 0; t < 2; t++) {
    float linv[4];
#pragma unroll
    for (int r = 0; r < 4; r++) linv[r] = 1.f / __shfl(lrow[t], quad * 4 + r);
#pragma unroll
    for (int dt = 0; dt < 8; dt++)
#pragma unroll
      for (int r = 0; r < 4; r++) {
        const int rowg = b * T_ + tIdx[t] * 64 + wave * 16 + quad * 4 + r;
        const int col = h * HD_ + dt * 16 + l16;
        O[(size_t)rowg * D_ + col] = f2bf(o[t][dt][r] * linv[r]);
      }
  }
}

extern "C" void kernel_launch(void* const* d_in, const int* in_sizes, int n_in,
                              void* d_out, int out_size, void* d_ws, size_t ws_size,
                              hipStream_t stream) {
  (void)in_sizes; (void)n_in; (void)out_size; (void)ws_size;
  const float* x  = (const float*)d_in[0];
  const float* wq = (const float*)d_in[2];
  const float* bq = (const float*)d_in[3];
  const float* wk = (const float*)d_in[4];
  const float* bk = (const float*)d_in[5];
  const float* wv = (const float*)d_in[6];
  const float* bv = (const float*)d_in[7];
  const float* wo = (const float*)d_in[8];
  const float* bo = (const float*)d_in[9];

  u16* ws  = (u16*)d_ws;
  u16* xb  = ws;                 // 8388608
  u16* wqb = ws + 8388608;
  u16* wkb = ws + 12582912;
  u16* wvb = ws + 16777216;
  u16* wob = ws + 20971520;
  u16* Qb  = ws + 25165824;
  u16* Kb  = ws + 33554432;
  u16* Vtb = ws + 41943040;      // [B,H,HD,T]
  u16* Ob  = ws + 50331648;

  cvt_kernel<<<8192, 256, 0, stream>>>(x, xb, 8388608);
  cvt4_kernel<<<dim3(4096, 4), 256, 0, stream>>>(wq, wk, wv, wo, wqb, wkb, wvb, wob, 4194304);

  dim3 gg(ND / 128, MROWS / 128, 3);
  gemm_qkv<<<gg, 256, 0, stream>>>(xb, wqb, wkb, wvb, bq, bk, bv, Qb, Kb, Vtb);
  attn_kernel<<<dim3(16, B_ * H_), 256, 0, stream>>>(Qb, Kb, Vtb, Ob);
  gemm_out<<<dim3(ND / 128, MROWS / 128), 256, 0, stream>>>(Ob, wob, bo, (float*)d_out);
}